// Round 1
// baseline (8049.553 us; speedup 1.0000x reference)
//
#include <hip/hip_runtime.h>
#include <math.h>

#define T_TOT 19200
#define HD    64
#define SKIPN 256
#define NLAYER 24
#define LFN   80
#define NB    2
#define TT    128   // t-tile per layer-kernel block
#define TT2   32    // t-tile per out-kernel block

// ---------------- upsample stage 1: y_up[b,g,t4] ----------------
__global__ __launch_bounds__(256) void up_kernel(
    const float* __restrict__ lf, const float* __restrict__ up_w,
    const float* __restrict__ up_b, float* __restrict__ y_up)
{
    int idx = blockIdx.x * 256 + threadIdx.x;
    if (idx >= NB * LFN * 256) return;
    int t4 = idx & 255;
    int g  = (idx >> 8) % LFN;
    int b  = idx / (LFN * 256);
    int l = t4 >> 2, k = t4 & 3;
    float acc = up_b[g];
    const float* lfp = lf + (b * 64 + l) * LFN;   // local_features[b,l,:]
    #pragma unroll 8
    for (int f = 0; f < LFN; ++f)
        acc += lfp[f] * up_w[(f * LFN + g) * 4 + k];
    y_up[idx] = acc;
}

// ---------------- upsample stage 2: z[b,o,t4] = proj ----------------
__global__ __launch_bounds__(256) void proj_kernel(
    const float* __restrict__ y_up, const float* __restrict__ proj_w,
    const float* __restrict__ proj_b, float* __restrict__ z)
{
    int idx = blockIdx.x * 256 + threadIdx.x;   // b*3072*256 + o*256 + t4
    if (idx >= NB * 3072 * 256) return;
    int t4 = idx & 255;
    int o  = (idx >> 8) % 3072;
    int b  = idx / (3072 * 256);
    float acc = proj_b[o];
    const float* yp = y_up + b * LFN * 256 + t4;
    const float* wp = proj_w + o * LFN;
    #pragma unroll 8
    for (int g = 0; g < LFN; ++g)
        acc += wp[g] * yp[g * 256];
    z[idx] = acc;
}

// ---------------- embed: x0[b,h,t] ----------------
__global__ __launch_bounds__(256) void embed_kernel(
    const float* __restrict__ gold, const float* __restrict__ ew,
    const float* __restrict__ eb, float* __restrict__ x)
{
    int idx = blockIdx.x * 256 + threadIdx.x;   // (b*64+h)*T + t
    if (idx >= NB * HD * T_TOT) return;
    int t = idx % T_TOT;
    int h = (idx / T_TOT) % HD;
    int b = idx / (HD * T_TOT);
    x[idx] = gold[b * T_TOT + t] * ew[h] + eb[h];
}

// ---------------- one WaveNet layer ----------------
// block: 256 threads; grid: (T/TT, B)
// thread: t = tid&127, half = tid>>7
__global__ __launch_bounds__(256) void layer_kernel(
    const float* __restrict__ x_in, float* __restrict__ x_out,
    const float* __restrict__ z,      // full z base
    const float* __restrict__ dil_w,  // already offset to layer: [128][64][2]
    const float* __restrict__ dil_b,  // [128]
    const float* __restrict__ skip_w, // [256][64]
    const float* __restrict__ skip_b, // [256]
    const float* __restrict__ res_w,  // [64][64]
    const float* __restrict__ res_b,  // [64]
    float* __restrict__ skip_sum,
    int layer, int dil, int first, int do_res)
{
    __shared__ float xs[HD][TT + 32];   // [h][t - t0 + 32]
    __shared__ float gs[HD][TT];        // gated

    const int b   = blockIdx.y;
    const int t0  = blockIdx.x * TT;
    const int tid = threadIdx.x;

    // ---- load x tile with 32-sample left halo (coalesced along t) ----
    for (int idx = tid; idx < HD * (TT + 32); idx += 256) {
        int h  = idx / (TT + 32);
        int tl = idx % (TT + 32);
        int tg = t0 + tl - 32;
        xs[h][tl] = (tg >= 0) ? x_in[(b * HD + h) * T_TOT + tg] : 0.0f;
    }
    __syncthreads();

    const int t    = tid & (TT - 1);
    const int half = tid >> 7;           // 0/1
    const int tg   = t0 + t;
    const int q    = tg / 75;            // cond repeat index
    const float* zb = z + (size_t)(b * 3072 + layer * 128) * 256 + q;

    // ---- dilated conv + gate: this thread covers h in [half*32, half*32+32) ----
    for (int hi = 0; hi < 32; ++hi) {
        int h = half * 32 + hi;
        const float* w0 = dil_w + h * 128;          // [hh][tap], tap stride 1
        const float* w1 = dil_w + (h + 64) * 128;
        float a0 = dil_b[h]      + zb[h * 256];
        float a1 = dil_b[h + 64] + zb[(h + 64) * 256];
        #pragma unroll 8
        for (int hh = 0; hh < HD; ++hh) {
            float xm = xs[hh][t + 32 - dil];
            float xc = xs[hh][t + 32];
            a0 += w0[hh * 2] * xm + w0[hh * 2 + 1] * xc;
            a1 += w1[hh * 2] * xm + w1[hh * 2 + 1] * xc;
        }
        float sg = 1.0f / (1.0f + __expf(-a1));
        gs[h][t] = tanhf(a0) * sg;
    }
    __syncthreads();

    // ---- cache gated column in registers (reused by skip 128x and res 32x) ----
    float gv[HD];
    #pragma unroll
    for (int hh = 0; hh < HD; ++hh) gv[hh] = gs[hh][t];

    // ---- skip: this thread covers s in [half*128, half*128+128) ----
    for (int si = 0; si < 128; ++si) {
        int s = half * 128 + si;
        float acc = skip_b[s];
        const float* w = skip_w + s * HD;
        #pragma unroll
        for (int hh = 0; hh < HD; ++hh) acc += w[hh] * gv[hh];
        float* sp = skip_sum + (size_t)(b * SKIPN + s) * T_TOT + tg;
        if (first) *sp = acc;
        else       *sp += acc;
    }

    // ---- residual: x_out = x + res_w @ gated ----
    if (do_res) {
        for (int hi = 0; hi < 32; ++hi) {
            int h = half * 32 + hi;
            float acc = res_b[h];
            const float* w = res_w + h * HD;
            #pragma unroll
            for (int hh = 0; hh < HD; ++hh) acc += w[hh] * gv[hh];
            x_out[(b * HD + h) * T_TOT + tg] = xs[h][t + 32] + acc;
        }
    }
}

// ---------------- output head: relu->W1->relu->W2->log_softmax ----------------
// block: 256 threads; grid: (T/TT2, B); thread: t = tid&31, og = tid>>5 (8 groups of 32 out-ch)
__global__ __launch_bounds__(256) void out_kernel(
    const float* __restrict__ skip_sum, const float* __restrict__ w1,
    const float* __restrict__ w2, float* __restrict__ out)
{
    __shared__ float vs[SKIPN][TT2];
    __shared__ float hs[SKIPN][TT2];
    __shared__ float red[8][TT2];

    const int b   = blockIdx.y;
    const int t0  = blockIdx.x * TT2;
    const int tid = threadIdx.x;

    for (int idx = tid; idx < SKIPN * TT2; idx += 256) {
        int s  = idx / TT2;
        int tl = idx % TT2;
        float v = skip_sum[(size_t)(b * SKIPN + s) * T_TOT + t0 + tl];
        vs[s][tl] = fmaxf(v, 0.0f);
    }
    __syncthreads();

    const int t  = tid & (TT2 - 1);
    const int og = tid >> 5;   // 0..7

    // h1 = relu(W1 @ v)
    float h1v[32];
    for (int oi = 0; oi < 32; ++oi) {
        int o = og * 32 + oi;
        float acc = 0.0f;
        const float* w = w1 + o * SKIPN;
        #pragma unroll 8
        for (int k = 0; k < SKIPN; ++k) acc += w[k] * vs[k][t];
        h1v[oi] = fmaxf(acc, 0.0f);
    }
    #pragma unroll
    for (int oi = 0; oi < 32; ++oi) hs[og * 32 + oi][t] = h1v[oi];
    __syncthreads();

    // h2 = W2 @ h1
    float h2v[32];
    float mymax = -1e30f;
    for (int oi = 0; oi < 32; ++oi) {
        int o = og * 32 + oi;
        float acc = 0.0f;
        const float* w = w2 + o * SKIPN;
        #pragma unroll 8
        for (int k = 0; k < SKIPN; ++k) acc += w[k] * hs[k][t];
        h2v[oi] = acc;
        mymax = fmaxf(mymax, acc);
    }

    // log-softmax over the 256 channels (8 groups x 32)
    red[og][t] = mymax;
    __syncthreads();
    float m = red[0][t];
    #pragma unroll
    for (int g = 1; g < 8; ++g) m = fmaxf(m, red[g][t]);
    float mysum = 0.0f;
    #pragma unroll
    for (int oi = 0; oi < 32; ++oi) mysum += __expf(h2v[oi] - m);
    __syncthreads();
    red[og][t] = mysum;
    __syncthreads();
    float ssum = 0.0f;
    #pragma unroll
    for (int g = 0; g < 8; ++g) ssum += red[g][t];
    float lse = m + logf(ssum);

    #pragma unroll
    for (int oi = 0; oi < 32; ++oi) {
        int o = og * 32 + oi;
        out[(size_t)(b * SKIPN + o) * T_TOT + t0 + t] = h2v[oi] - lse;
    }
}

extern "C" void kernel_launch(void* const* d_in, const int* in_sizes, int n_in,
                              void* d_out, int out_size, void* d_ws, size_t ws_size,
                              hipStream_t stream) {
    const float* lf       = (const float*)d_in[0];
    const float* gold     = (const float*)d_in[1];
    const float* embed_w  = (const float*)d_in[2];
    const float* embed_b  = (const float*)d_in[3];
    const float* up_w     = (const float*)d_in[4];
    const float* up_b     = (const float*)d_in[5];
    const float* proj_w   = (const float*)d_in[6];
    const float* proj_b   = (const float*)d_in[7];
    const float* dil_w    = (const float*)d_in[8];
    const float* dil_b    = (const float*)d_in[9];
    const float* skip_w   = (const float*)d_in[10];
    const float* skip_b   = (const float*)d_in[11];
    const float* res_w    = (const float*)d_in[12];
    const float* res_b    = (const float*)d_in[13];
    const float* out1_w   = (const float*)d_in[14];
    const float* out2_w   = (const float*)d_in[15];

    float* ws      = (float*)d_ws;
    float* y_up    = ws;                          // 2*80*256      = 40960
    float* z       = y_up + NB * LFN * 256;       // 2*3072*256    = 1572864
    float* x_a     = z + NB * 3072 * 256;         // 2*64*19200    = 2457600
    float* x_b     = x_a + NB * HD * T_TOT;       // 2457600
    float* skipsum = x_b + NB * HD * T_TOT;       // 2*256*19200   = 9830400

    up_kernel  <<<(NB * LFN * 256 + 255) / 256, 256, 0, stream>>>(lf, up_w, up_b, y_up);
    proj_kernel<<<(NB * 3072 * 256) / 256,      256, 0, stream>>>(y_up, proj_w, proj_b, z);
    embed_kernel<<<(NB * HD * T_TOT) / 256,     256, 0, stream>>>(gold, embed_w, embed_b, x_a);

    float* xin = x_a;
    float* xout = x_b;
    for (int i = 0; i < NLAYER; ++i) {
        int d = 1 << (i % 6);
        layer_kernel<<<dim3(T_TOT / TT, NB), 256, 0, stream>>>(
            xin, xout, z,
            dil_w + (size_t)i * 128 * 64 * 2, dil_b + i * 128,
            skip_w + (size_t)i * 256 * 64,    skip_b + i * 256,
            (i < NLAYER - 1) ? res_w + (size_t)i * 64 * 64 : res_w,
            (i < NLAYER - 1) ? res_b + i * 64 : res_b,
            skipsum, i, d, (i == 0) ? 1 : 0, (i < NLAYER - 1) ? 1 : 0);
        float* tmp = xin; xin = xout; xout = tmp;
    }

    out_kernel<<<dim3(T_TOT / TT2, NB), 256, 0, stream>>>(skipsum, out1_w, out2_w, (float*)d_out);
}

// Round 2
// 1331.694 us; speedup vs baseline: 6.0446x; 6.0446x over previous
//
#include <hip/hip_runtime.h>
#include <math.h>

#define T_TOT 19200
#define HD    64
#define SKIPN 256
#define NLAYER 24
#define LFN   80
#define NB    2
#define NT    64    // t-tile per layer block
#define NO    64    // t-tile per out block

typedef float  f32x4  __attribute__((ext_vector_type(4)));
typedef __bf16 bf16x8 __attribute__((ext_vector_type(8)));

__device__ __forceinline__ f32x4 mfma16(bf16x8 a, bf16x8 b, f32x4 c) {
    return __builtin_amdgcn_mfma_f32_16x16x32_bf16(a, b, c, 0, 0, 0);
}

// ---------------- weight conversion to bf16 ----------------
// A1[24][128][128]: k<64 -> dil_w[l][o][k][0] (t-d tap), k>=64 -> dil_w[l][o][k-64][1]
// A2 = skip_w verbatim, A3 = res_w verbatim, Ao1/Ao2 = out heads verbatim
__global__ __launch_bounds__(256) void prep_kernel(
    const float* __restrict__ dil_w, const float* __restrict__ skip_w,
    const float* __restrict__ res_w, const float* __restrict__ out1_w,
    const float* __restrict__ out2_w,
    __bf16* __restrict__ A1, __bf16* __restrict__ A2, __bf16* __restrict__ A3,
    __bf16* __restrict__ Ao1, __bf16* __restrict__ Ao2)
{
    int idx = blockIdx.x * 256 + threadIdx.x;
    if (idx < 24 * 128 * 128) {
        int k = idx & 127, o = (idx >> 7) & 127, l = idx >> 14;
        A1[idx] = (__bf16)dil_w[((l * 128 + o) * 64 + (k & 63)) * 2 + (k >> 6)];
        A2[idx] = (__bf16)skip_w[idx];           // 24*256*64 == 24*128*128
    }
    if (idx < 23 * 64 * 64)  A3[idx]  = (__bf16)res_w[idx];
    if (idx < 256 * 256)   { Ao1[idx] = (__bf16)out1_w[idx];
                             Ao2[idx] = (__bf16)out2_w[idx]; }
}

// ---------------- upsample stage 1 ----------------
__global__ __launch_bounds__(256) void up_kernel(
    const float* __restrict__ lf, const float* __restrict__ up_w,
    const float* __restrict__ up_b, float* __restrict__ y_up)
{
    int idx = blockIdx.x * 256 + threadIdx.x;
    if (idx >= NB * LFN * 256) return;
    int t4 = idx & 255;
    int g  = (idx >> 8) % LFN;
    int b  = idx / (LFN * 256);
    int l = t4 >> 2, k = t4 & 3;
    float acc = up_b[g];
    const float* lfp = lf + (b * 64 + l) * LFN;
    #pragma unroll 8
    for (int f = 0; f < LFN; ++f)
        acc += lfp[f] * up_w[(f * LFN + g) * 4 + k];
    y_up[idx] = acc;
}

// ---------------- upsample stage 2 ----------------
__global__ __launch_bounds__(256) void proj_kernel(
    const float* __restrict__ y_up, const float* __restrict__ proj_w,
    const float* __restrict__ proj_b, float* __restrict__ z)
{
    int idx = blockIdx.x * 256 + threadIdx.x;
    if (idx >= NB * 3072 * 256) return;
    int t4 = idx & 255;
    int o  = (idx >> 8) % 3072;
    int b  = idx / (3072 * 256);
    float acc = proj_b[o];
    const float* yp = y_up + b * LFN * 256 + t4;
    const float* wp = proj_w + o * LFN;
    #pragma unroll 8
    for (int g = 0; g < LFN; ++g)
        acc += wp[g] * yp[g * 256];
    z[idx] = acc;
}

// ---------------- embed ----------------
__global__ __launch_bounds__(256) void embed_kernel(
    const float* __restrict__ gold, const float* __restrict__ ew,
    const float* __restrict__ eb, float* __restrict__ x)
{
    int idx = blockIdx.x * 256 + threadIdx.x;
    if (idx >= NB * HD * T_TOT) return;
    int t = idx % T_TOT;
    int h = (idx / T_TOT) % HD;
    int b = idx / (HD * T_TOT);
    x[idx] = gold[b * T_TOT + t] * ew[h] + eb[h];
}

// ---------------- one WaveNet layer, MFMA ----------------
// grid: (T/NT, B), 256 threads (4 waves). Wave w owns:
//  GEMM1 rows [w*16,w*16+16) (tanh) and [64+w*16, 64+w*16+16) (sigmoid)
//  GEMM2 rows [w*64, w*64+64), GEMM3 rows [w*16, w*16+16)
__global__ __launch_bounds__(256) void layer_mfma(
    const float* __restrict__ x_in, float* __restrict__ x_out,
    const float* __restrict__ z,
    const __bf16* __restrict__ A1, const float* __restrict__ dil_b,
    const __bf16* __restrict__ A2, const float* __restrict__ skip_b,
    const __bf16* __restrict__ A3, const float* __restrict__ res_b,
    float* __restrict__ skip_sum, int layer, int dil, int first, int do_res)
{
    __shared__ __bf16 Bx[NT][136];   // xcat B-operand [n][k], row 272B (16B-aligned)
    __shared__ __bf16 Gs[NT][72];    // gated  B-operand [n][h], row 144B

    const int b    = blockIdx.y;
    const int t0   = blockIdx.x * NT;
    const int tid  = threadIdx.x;
    const int lane = tid & 63;
    const int w    = tid >> 6;
    const int n16  = lane & 15;
    const int quad = lane >> 4;

    // stage xcat: k<64 -> x[k][t-dil], k>=64 -> x[k-64][t]  (bf16)
    for (int idx = tid; idx < 128 * NT; idx += 256) {
        int n = idx & (NT - 1);
        int k = idx >> 6;
        int h = k & 63;
        int t = t0 + n - ((k < 64) ? dil : 0);
        float v = (t >= 0) ? x_in[((size_t)(b * HD + h)) * T_TOT + t] : 0.0f;
        Bx[n][k] = (__bf16)v;
    }

    // A1 fragments in registers (row stride 128 bf16 = 16 vecs)
    const bf16x8* A1v = (const bf16x8*)A1;
    bf16x8 a1a[4], a1b[4];
    {
        int ra = w * 16 + n16;
        int rb = 64 + w * 16 + n16;
        #pragma unroll
        for (int ks = 0; ks < 4; ++ks) {
            a1a[ks] = A1v[ra * 16 + ks * 4 + quad];
            a1b[ks] = A1v[rb * 16 + ks * 4 + quad];
        }
    }
    __syncthreads();

    // GEMM1: K=128 (4 k-steps), N=64 (4 n-tiles)
    f32x4 zero4 = {0.0f, 0.0f, 0.0f, 0.0f};
    f32x4 acc_a[4], acc_b[4];
    #pragma unroll
    for (int nt = 0; nt < 4; ++nt) { acc_a[nt] = zero4; acc_b[nt] = zero4; }
    #pragma unroll
    for (int ks = 0; ks < 4; ++ks) {
        #pragma unroll
        for (int nt = 0; nt < 4; ++nt) {
            bf16x8 bf = *(const bf16x8*)&Bx[nt * 16 + n16][ks * 32 + quad * 8];
            acc_a[nt] = mfma16(a1a[ks], bf, acc_a[nt]);
            acc_b[nt] = mfma16(a1b[ks], bf, acc_b[nt]);
        }
    }

    // gate epilogue: + bias + cond, tanh*sigmoid -> Gs (bf16)
    const float* zb = z + ((size_t)b * 3072 + layer * 128) * 256;
    #pragma unroll
    for (int nt = 0; nt < 4; ++nt) {
        int t = t0 + nt * 16 + n16;
        int q = t / 75;
        #pragma unroll
        for (int r = 0; r < 4; ++r) {
            int o = w * 16 + quad * 4 + r;
            float ya = acc_a[nt][r] + dil_b[o]      + zb[o * 256 + q];
            float yb = acc_b[nt][r] + dil_b[o + 64] + zb[(o + 64) * 256 + q];
            float g = tanhf(ya) * (1.0f / (1.0f + __expf(-yb)));
            Gs[nt * 16 + n16][o] = (__bf16)g;
        }
    }
    __syncthreads();

    // A2 / A3 fragments (row strides: 64 bf16 = 8 vecs)
    const bf16x8* A2v = (const bf16x8*)A2;
    const bf16x8* A3v = (const bf16x8*)A3;
    bf16x8 a2[4][2];
    #pragma unroll
    for (int mt = 0; mt < 4; ++mt)
        #pragma unroll
        for (int ks = 0; ks < 2; ++ks)
            a2[mt][ks] = A2v[(w * 64 + mt * 16 + n16) * 8 + ks * 4 + quad];
    bf16x8 a3[2];
    if (do_res) {
        #pragma unroll
        for (int ks = 0; ks < 2; ++ks)
            a3[ks] = A3v[(w * 16 + n16) * 8 + ks * 4 + quad];
    }

    // GEMM2 (skip, K=64) + GEMM3 (res, K=64), epilogues fused per n-tile
    #pragma unroll
    for (int nt = 0; nt < 4; ++nt) {
        bf16x8 bf0 = *(const bf16x8*)&Gs[nt * 16 + n16][quad * 8];
        bf16x8 bf1 = *(const bf16x8*)&Gs[nt * 16 + n16][32 + quad * 8];
        int t = t0 + nt * 16 + n16;
        #pragma unroll
        for (int mt = 0; mt < 4; ++mt) {
            f32x4 acc = zero4;
            acc = mfma16(a2[mt][0], bf0, acc);
            acc = mfma16(a2[mt][1], bf1, acc);
            #pragma unroll
            for (int r = 0; r < 4; ++r) {
                int s = w * 64 + mt * 16 + quad * 4 + r;
                float v = acc[r] + skip_b[s];
                float* sp = skip_sum + ((size_t)(b * SKIPN + s)) * T_TOT + t;
                if (first) *sp = v;
                else       *sp += v;
            }
        }
        if (do_res) {
            f32x4 acc = zero4;
            acc = mfma16(a3[0], bf0, acc);
            acc = mfma16(a3[1], bf1, acc);
            #pragma unroll
            for (int r = 0; r < 4; ++r) {
                int o = w * 16 + quad * 4 + r;
                size_t off = ((size_t)(b * HD + o)) * T_TOT + t;
                x_out[off] = x_in[off] + acc[r] + res_b[o];
            }
        }
    }
}

// ---------------- output head, MFMA + log-softmax ----------------
// grid: (T/NO, B), 256 threads. Wave w owns rows [w*64, w*64+64) of each GEMM.
__global__ __launch_bounds__(256) void out_mfma(
    const float* __restrict__ skip_sum, const __bf16* __restrict__ W1,
    const __bf16* __restrict__ W2, float* __restrict__ out)
{
    __shared__ __bf16 Vs[NO][264];   // relu(skip_sum) B-operand, row 528B
    __shared__ __bf16 Hs[NO][264];   // relu(h1)       B-operand
    __shared__ float redm[4][4][16];
    __shared__ float reds[4][4][16];

    const int b    = blockIdx.y;
    const int t0   = blockIdx.x * NO;
    const int tid  = threadIdx.x;
    const int lane = tid & 63;
    const int w    = tid >> 6;
    const int n16  = lane & 15;
    const int quad = lane >> 4;

    for (int idx = tid; idx < 256 * NO; idx += 256) {
        int n = idx & (NO - 1);
        int k = idx >> 6;
        float v = skip_sum[((size_t)(b * SKIPN + k)) * T_TOT + t0 + n];
        Vs[n][k] = (__bf16)fmaxf(v, 0.0f);
    }
    __syncthreads();

    f32x4 zero4 = {0.0f, 0.0f, 0.0f, 0.0f};
    const bf16x8* W1v = (const bf16x8*)W1;   // row stride 256 bf16 = 32 vecs
    const bf16x8* W2v = (const bf16x8*)W2;

    // GEMM1: h1 = W1 @ relu(v), K=256 (8 k-steps)
    f32x4 acc[4][4];
    #pragma unroll
    for (int mt = 0; mt < 4; ++mt)
        #pragma unroll
        for (int nt = 0; nt < 4; ++nt) acc[mt][nt] = zero4;
    #pragma unroll
    for (int ks = 0; ks < 8; ++ks) {
        bf16x8 bfr[4];
        #pragma unroll
        for (int nt = 0; nt < 4; ++nt)
            bfr[nt] = *(const bf16x8*)&Vs[nt * 16 + n16][ks * 32 + quad * 8];
        #pragma unroll
        for (int mt = 0; mt < 4; ++mt) {
            bf16x8 af = W1v[(w * 64 + mt * 16 + n16) * 32 + ks * 4 + quad];
            #pragma unroll
            for (int nt = 0; nt < 4; ++nt)
                acc[mt][nt] = mfma16(af, bfr[nt], acc[mt][nt]);
        }
    }
    // relu -> Hs
    #pragma unroll
    for (int mt = 0; mt < 4; ++mt)
        #pragma unroll
        for (int nt = 0; nt < 4; ++nt)
            #pragma unroll
            for (int r = 0; r < 4; ++r)
                Hs[nt * 16 + n16][w * 64 + mt * 16 + quad * 4 + r] =
                    (__bf16)fmaxf(acc[mt][nt][r], 0.0f);
    __syncthreads();

    // GEMM2: h2 = W2 @ relu(h1)
    #pragma unroll
    for (int mt = 0; mt < 4; ++mt)
        #pragma unroll
        for (int nt = 0; nt < 4; ++nt) acc[mt][nt] = zero4;
    #pragma unroll
    for (int ks = 0; ks < 8; ++ks) {
        bf16x8 bfr[4];
        #pragma unroll
        for (int nt = 0; nt < 4; ++nt)
            bfr[nt] = *(const bf16x8*)&Hs[nt * 16 + n16][ks * 32 + quad * 8];
        #pragma unroll
        for (int mt = 0; mt < 4; ++mt) {
            bf16x8 af = W2v[(w * 64 + mt * 16 + n16) * 32 + ks * 4 + quad];
            #pragma unroll
            for (int nt = 0; nt < 4; ++nt)
                acc[mt][nt] = mfma16(af, bfr[nt], acc[mt][nt]);
        }
    }

    // log-softmax over 256 rows per column
    float lmax[4], lsum[4];
    #pragma unroll
    for (int nt = 0; nt < 4; ++nt) {
        float m = -1e30f;
        #pragma unroll
        for (int mt = 0; mt < 4; ++mt)
            #pragma unroll
            for (int r = 0; r < 4; ++r) m = fmaxf(m, acc[mt][nt][r]);
        m = fmaxf(m, __shfl_xor(m, 16, 64));
        m = fmaxf(m, __shfl_xor(m, 32, 64));
        lmax[nt] = m;
    }
    if (quad == 0) {
        #pragma unroll
        for (int nt = 0; nt < 4; ++nt) redm[w][nt][n16] = lmax[nt];
    }
    __syncthreads();
    #pragma unroll
    for (int nt = 0; nt < 4; ++nt) {
        float m = redm[0][nt][n16];
        m = fmaxf(m, redm[1][nt][n16]);
        m = fmaxf(m, redm[2][nt][n16]);
        m = fmaxf(m, redm[3][nt][n16]);
        lmax[nt] = m;
        float s = 0.0f;
        #pragma unroll
        for (int mt = 0; mt < 4; ++mt)
            #pragma unroll
            for (int r = 0; r < 4; ++r) s += __expf(acc[mt][nt][r] - m);
        s += __shfl_xor(s, 16, 64);
        s += __shfl_xor(s, 32, 64);
        lsum[nt] = s;
    }
    if (quad == 0) {
        #pragma unroll
        for (int nt = 0; nt < 4; ++nt) reds[w][nt][n16] = lsum[nt];
    }
    __syncthreads();
    #pragma unroll
    for (int nt = 0; nt < 4; ++nt) {
        float s = reds[0][nt][n16] + reds[1][nt][n16] + reds[2][nt][n16] + reds[3][nt][n16];
        float lse = lmax[nt] + logf(s);
        int t = t0 + nt * 16 + n16;
        #pragma unroll
        for (int mt = 0; mt < 4; ++mt)
            #pragma unroll
            for (int r = 0; r < 4; ++r) {
                int o = w * 64 + mt * 16 + quad * 4 + r;
                out[((size_t)(b * SKIPN + o)) * T_TOT + t] = acc[mt][nt][r] - lse;
            }
    }
}

extern "C" void kernel_launch(void* const* d_in, const int* in_sizes, int n_in,
                              void* d_out, int out_size, void* d_ws, size_t ws_size,
                              hipStream_t stream) {
    const float* lf       = (const float*)d_in[0];
    const float* gold     = (const float*)d_in[1];
    const float* embed_w  = (const float*)d_in[2];
    const float* embed_b  = (const float*)d_in[3];
    const float* up_w     = (const float*)d_in[4];
    const float* up_b     = (const float*)d_in[5];
    const float* proj_w   = (const float*)d_in[6];
    const float* proj_b   = (const float*)d_in[7];
    const float* dil_w    = (const float*)d_in[8];
    const float* dil_b    = (const float*)d_in[9];
    const float* skip_w   = (const float*)d_in[10];
    const float* skip_b   = (const float*)d_in[11];
    const float* res_w    = (const float*)d_in[12];
    const float* res_b    = (const float*)d_in[13];
    const float* out1_w   = (const float*)d_in[14];
    const float* out2_w   = (const float*)d_in[15];

    // bf16 weights first (16B-aligned segments), then f32 buffers
    __bf16* A1  = (__bf16*)d_ws;          // 24*128*128 = 393216
    __bf16* A2  = A1 + 393216;            // 24*256*64  = 393216
    __bf16* A3  = A2 + 393216;            // 23*64*64   = 94208
    __bf16* Ao1 = A3 + 94208;             // 256*256    = 65536
    __bf16* Ao2 = Ao1 + 65536;            // 256*256    = 65536
    float* y_up    = (float*)(Ao2 + 65536);
    float* z       = y_up + NB * LFN * 256;        // 2*3072*256
    float* x_a     = z + NB * 3072 * 256;          // 2*64*19200
    float* x_b     = x_a + NB * HD * T_TOT;
    float* skipsum = x_b + NB * HD * T_TOT;        // 2*256*19200

    prep_kernel<<<(24 * 128 * 128 + 255) / 256, 256, 0, stream>>>(
        dil_w, skip_w, res_w, out1_w, out2_w, A1, A2, A3, Ao1, Ao2);
    up_kernel  <<<(NB * LFN * 256 + 255) / 256, 256, 0, stream>>>(lf, up_w, up_b, y_up);
    proj_kernel<<<(NB * 3072 * 256) / 256,      256, 0, stream>>>(y_up, proj_w, proj_b, z);
    embed_kernel<<<(NB * HD * T_TOT) / 256,     256, 0, stream>>>(gold, embed_w, embed_b, x_a);

    float* xin = x_a;
    float* xout = x_b;
    for (int i = 0; i < NLAYER; ++i) {
        int d = 1 << (i % 6);
        layer_mfma<<<dim3(T_TOT / NT, NB), 256, 0, stream>>>(
            xin, xout, z,
            A1 + (size_t)i * 128 * 128, dil_b + i * 128,
            A2 + (size_t)i * 256 * 64,  skip_b + i * 256,
            (i < NLAYER - 1) ? A3 + (size_t)i * 64 * 64 : A3,
            (i < NLAYER - 1) ? res_b + i * 64 : res_b,
            skipsum, i, d, (i == 0) ? 1 : 0, (i < NLAYER - 1) ? 1 : 0);
        float* tmp = xin; xin = xout; xout = tmp;
    }

    out_mfma<<<dim3(T_TOT / NO, NB), 256, 0, stream>>>(skipsum, Ao1, Ao2, (float*)d_out);
}

// Round 3
// 733.775 us; speedup vs baseline: 10.9701x; 1.8149x over previous
//
#include <hip/hip_runtime.h>
#include <math.h>

#define T_TOT 19200
#define HD    64
#define SKIPN 256
#define NLAYER 24
#define LFN   80
#define NB    2
#define NT    64            // t-tile per layer block
#define NTILE (T_TOT / NT)  // 300
#define NO    64            // t-tile per head block

typedef float  f32x4  __attribute__((ext_vector_type(4)));
typedef __bf16 bf16x8 __attribute__((ext_vector_type(8)));
typedef __bf16 bf16x4 __attribute__((ext_vector_type(4)));

__device__ __forceinline__ f32x4 mfma16(bf16x8 a, bf16x8 b, f32x4 c) {
    return __builtin_amdgcn_mfma_f32_16x16x32_bf16(a, b, c, 0, 0, 0);
}

// ---------------- weight conversion to bf16 ----------------
__global__ __launch_bounds__(256) void prep_kernel(
    const float* __restrict__ dil_w, const float* __restrict__ skip_w,
    const float* __restrict__ skip_b, const float* __restrict__ res_w,
    const float* __restrict__ out1_w, const float* __restrict__ out2_w,
    __bf16* __restrict__ A1, __bf16* __restrict__ A3, __bf16* __restrict__ As1,
    __bf16* __restrict__ Ao1, __bf16* __restrict__ Ao2, float* __restrict__ sbsum)
{
    int idx = blockIdx.x * 256 + threadIdx.x;
    if (idx < 24 * 128 * 128) {
        // A1[l][o][k]: k<64 -> dil_w[l][o][k][0] (t-d tap), k>=64 -> tap t
        int k = idx & 127, o = (idx >> 7) & 127, l = idx >> 14;
        A1[idx] = (__bf16)dil_w[((l * 128 + o) * 64 + (k & 63)) * 2 + (k >> 6)];
        // As1[s][l*64+h] = skip_w[l][s][h]  (K=1536 concat layout)
        int kk = idx % 1536, s = idx / 1536;
        int ll = kk >> 6, h = kk & 63;
        As1[idx] = (__bf16)skip_w[(ll * 256 + s) * 64 + h];
    }
    if (idx < 23 * 64 * 64)  A3[idx]  = (__bf16)res_w[idx];
    if (idx < 256 * 256)   { Ao1[idx] = (__bf16)out1_w[idx];
                             Ao2[idx] = (__bf16)out2_w[idx]; }
    if (idx < 256) {
        float s = 0.0f;
        #pragma unroll
        for (int l = 0; l < 24; ++l) s += skip_b[l * 256 + idx];
        sbsum[idx] = s;
    }
}

// ---------------- upsample stage 1 ----------------
__global__ __launch_bounds__(256) void up_kernel(
    const float* __restrict__ lf, const float* __restrict__ up_w,
    const float* __restrict__ up_b, float* __restrict__ y_up)
{
    int idx = blockIdx.x * 256 + threadIdx.x;
    if (idx >= NB * LFN * 256) return;
    int t4 = idx & 255;
    int g  = (idx >> 8) % LFN;
    int b  = idx / (LFN * 256);
    int l = t4 >> 2, k = t4 & 3;
    float acc = up_b[g];
    const float* lfp = lf + (b * 64 + l) * LFN;
    #pragma unroll 8
    for (int f = 0; f < LFN; ++f)
        acc += lfp[f] * up_w[(f * LFN + g) * 4 + k];
    y_up[idx] = acc;
}

// ---------------- upsample stage 2 ----------------
__global__ __launch_bounds__(256) void proj_kernel(
    const float* __restrict__ y_up, const float* __restrict__ proj_w,
    const float* __restrict__ proj_b, float* __restrict__ z)
{
    int idx = blockIdx.x * 256 + threadIdx.x;
    if (idx >= NB * 3072 * 256) return;
    int t4 = idx & 255;
    int o  = (idx >> 8) % 3072;
    int b  = idx / (3072 * 256);
    float acc = proj_b[o];
    const float* yp = y_up + b * LFN * 256 + t4;
    const float* wp = proj_w + o * LFN;
    #pragma unroll 8
    for (int g = 0; g < LFN; ++g)
        acc += wp[g] * yp[g * 256];
    z[idx] = acc;
}

// ---------------- embed ----------------
__global__ __launch_bounds__(256) void embed_kernel(
    const float* __restrict__ gold, const float* __restrict__ ew,
    const float* __restrict__ eb, float* __restrict__ x)
{
    int idx = blockIdx.x * 256 + threadIdx.x;
    if (idx >= NB * HD * T_TOT) return;
    int t = idx % T_TOT;
    int h = (idx / T_TOT) % HD;
    int b = idx / (HD * T_TOT);
    x[idx] = gold[b * T_TOT + t] * ew[h] + eb[h];
}

// ---------------- one WaveNet layer, MFMA ----------------
// grid: (NTILE, B), 256 threads (4 waves). GEMM1 rows per wave: [w*16,+16) and
// [64+w*16,+16); res rows [w*16,+16). g (gated) tile goes to G in B-fragment layout.
__global__ __launch_bounds__(256) void layer_mfma(
    const float* __restrict__ x_in, float* __restrict__ x_out,
    const float* __restrict__ z,
    const __bf16* __restrict__ A1, const float* __restrict__ dil_b,
    const __bf16* __restrict__ A3, const float* __restrict__ res_b,
    __bf16* __restrict__ G, int layer, int dil, int do_res)
{
    __shared__ __bf16 Bx[NT][136];   // xcat B-operand [n][k]
    __shared__ __bf16 Gs[NT][72];    // gated [n][h]

    const int b    = blockIdx.y;
    const int tb   = blockIdx.x;
    const int t0   = tb * NT;
    const int tid  = threadIdx.x;
    const int lane = tid & 63;
    const int w    = tid >> 6;
    const int n16  = lane & 15;
    const int quad = lane >> 4;

    // stage xcat: k<64 -> x[k][t-dil], k>=64 -> x[k-64][t]
    for (int idx = tid; idx < 128 * NT; idx += 256) {
        int n = idx & (NT - 1);
        int k = idx >> 6;
        int h = k & 63;
        int t = t0 + n - ((k < 64) ? dil : 0);
        float v = (t >= 0) ? x_in[((size_t)(b * HD + h)) * T_TOT + t] : 0.0f;
        Bx[n][k] = (__bf16)v;
    }

    // A1 fragments (row stride 128 bf16 = 16 vecs)
    const bf16x8* A1v = (const bf16x8*)A1;
    bf16x8 a1a[4], a1b[4];
    {
        int ra = w * 16 + n16;
        int rb = 64 + w * 16 + n16;
        #pragma unroll
        for (int ks = 0; ks < 4; ++ks) {
            a1a[ks] = A1v[ra * 16 + ks * 4 + quad];
            a1b[ks] = A1v[rb * 16 + ks * 4 + quad];
        }
    }
    __syncthreads();

    // GEMM1: K=128, N=64
    f32x4 zero4 = {0.0f, 0.0f, 0.0f, 0.0f};
    f32x4 acc_a[4], acc_b[4];
    #pragma unroll
    for (int nt = 0; nt < 4; ++nt) { acc_a[nt] = zero4; acc_b[nt] = zero4; }
    #pragma unroll
    for (int ks = 0; ks < 4; ++ks) {
        #pragma unroll
        for (int nt = 0; nt < 4; ++nt) {
            bf16x8 bf = *(const bf16x8*)&Bx[nt * 16 + n16][ks * 32 + quad * 8];
            acc_a[nt] = mfma16(a1a[ks], bf, acc_a[nt]);
            acc_b[nt] = mfma16(a1b[ks], bf, acc_b[nt]);
        }
    }

    // gate epilogue: +bias +cond, tanh*sigmoid (fast exp/rcp) -> Gs
    const float* zb = z + ((size_t)b * 3072 + layer * 128) * 256;
    #pragma unroll
    for (int nt = 0; nt < 4; ++nt) {
        int t = t0 + nt * 16 + n16;
        int q = t / 75;
        #pragma unroll
        for (int r = 0; r < 4; ++r) {
            int o = w * 16 + quad * 4 + r;
            float ya = acc_a[nt][r] + dil_b[o]      + zb[o * 256 + q];
            float yb = acc_b[nt][r] + dil_b[o + 64] + zb[(o + 64) * 256 + q];
            float e2 = __expf(2.0f * ya);
            float th = 1.0f - 2.0f * __builtin_amdgcn_rcpf(e2 + 1.0f);
            float sg = __builtin_amdgcn_rcpf(1.0f + __expf(-yb));
            Gs[nt * 16 + n16][o] = (__bf16)(th * sg);
        }
    }
    __syncthreads();

    // write gated tile to G (B-fragment layout: [n][h], h contiguous)
    __bf16* Gt = G + (((size_t)layer * NB + b) * NTILE + tb) * (NT * HD);
    for (int idx = tid; idx < NT * HD / 4; idx += 256) {
        int n  = idx >> 4;
        int hq = (idx & 15) * 4;
        bf16x4 v = *(const bf16x4*)&Gs[n][hq];
        *(bf16x4*)&Gt[n * HD + hq] = v;
    }

    // residual GEMM: x_out = x_in + res_w @ g + res_b
    if (do_res) {
        const bf16x8* A3v = (const bf16x8*)A3;
        bf16x8 a3[2];
        #pragma unroll
        for (int ks = 0; ks < 2; ++ks)
            a3[ks] = A3v[(w * 16 + n16) * 8 + ks * 4 + quad];
        #pragma unroll
        for (int nt = 0; nt < 4; ++nt) {
            bf16x8 bf0 = *(const bf16x8*)&Gs[nt * 16 + n16][quad * 8];
            bf16x8 bf1 = *(const bf16x8*)&Gs[nt * 16 + n16][32 + quad * 8];
            int t = t0 + nt * 16 + n16;
            f32x4 acc = zero4;
            acc = mfma16(a3[0], bf0, acc);
            acc = mfma16(a3[1], bf1, acc);
            #pragma unroll
            for (int r = 0; r < 4; ++r) {
                int o = w * 16 + quad * 4 + r;
                size_t off = ((size_t)(b * HD + o)) * T_TOT + t;
                x_out[off] = x_in[off] + acc[r] + res_b[o];
            }
        }
    }
}

// ---------------- fused head: skip-sum GEMM (K=1536) + out1 + out2 + log-softmax ----
// grid: (NTILE, B), 256 threads. Wave w owns rows [w*64, w*64+64) of each GEMM.
__global__ __launch_bounds__(256) void head_mfma(
    const __bf16* __restrict__ G, const __bf16* __restrict__ As1,
    const float* __restrict__ sbsum, const __bf16* __restrict__ W1,
    const __bf16* __restrict__ W2, float* __restrict__ out)
{
    __shared__ __bf16 Vs[NO][264];   // relu(skip_sum) B-operand
    __shared__ __bf16 Hs[NO][264];   // relu(h1)       B-operand
    __shared__ float redm[4][4][16];
    __shared__ float reds[4][4][16];

    const int b    = blockIdx.y;
    const int tb   = blockIdx.x;
    const int t0   = tb * NO;
    const int tid  = threadIdx.x;
    const int lane = tid & 63;
    const int w    = tid >> 6;
    const int n16  = lane & 15;
    const int quad = lane >> 4;

    f32x4 zero4 = {0.0f, 0.0f, 0.0f, 0.0f};
    f32x4 acc[4][4];
    #pragma unroll
    for (int mt = 0; mt < 4; ++mt)
        #pragma unroll
        for (int nt = 0; nt < 4; ++nt) acc[mt][nt] = zero4;

    // phase 1: skip = sum_l skip_w[l] @ g[l]  (K = 24*64, B-frags straight from G)
    const bf16x8* Asv = (const bf16x8*)As1;   // row stride 1536 bf16 = 192 vecs
    for (int l = 0; l < NLAYER; ++l) {
        const __bf16* Gt = G + (((size_t)l * NB + b) * NTILE + tb) * (NT * HD);
        #pragma unroll
        for (int ks = 0; ks < 2; ++ks) {
            bf16x8 bfr[4];
            #pragma unroll
            for (int nt = 0; nt < 4; ++nt)
                bfr[nt] = *(const bf16x8*)&Gt[(nt * 16 + n16) * HD + ks * 32 + quad * 8];
            #pragma unroll
            for (int mt = 0; mt < 4; ++mt) {
                bf16x8 af = Asv[(w * 64 + mt * 16 + n16) * 192 + l * 8 + ks * 4 + quad];
                #pragma unroll
                for (int nt = 0; nt < 4; ++nt)
                    acc[mt][nt] = mfma16(af, bfr[nt], acc[mt][nt]);
            }
        }
    }
    // epilogue: + bias-sum, relu -> Vs
    #pragma unroll
    for (int mt = 0; mt < 4; ++mt)
        #pragma unroll
        for (int nt = 0; nt < 4; ++nt)
            #pragma unroll
            for (int r = 0; r < 4; ++r) {
                int s = w * 64 + mt * 16 + quad * 4 + r;
                Vs[nt * 16 + n16][s] = (__bf16)fmaxf(acc[mt][nt][r] + sbsum[s], 0.0f);
            }
    __syncthreads();

    const bf16x8* W1v = (const bf16x8*)W1;   // row stride 256 bf16 = 32 vecs
    const bf16x8* W2v = (const bf16x8*)W2;

    // phase 2: h1 = relu(W1 @ v), K=256
    #pragma unroll
    for (int mt = 0; mt < 4; ++mt)
        #pragma unroll
        for (int nt = 0; nt < 4; ++nt) acc[mt][nt] = zero4;
    #pragma unroll
    for (int ks = 0; ks < 8; ++ks) {
        bf16x8 bfr[4];
        #pragma unroll
        for (int nt = 0; nt < 4; ++nt)
            bfr[nt] = *(const bf16x8*)&Vs[nt * 16 + n16][ks * 32 + quad * 8];
        #pragma unroll
        for (int mt = 0; mt < 4; ++mt) {
            bf16x8 af = W1v[(w * 64 + mt * 16 + n16) * 32 + ks * 4 + quad];
            #pragma unroll
            for (int nt = 0; nt < 4; ++nt)
                acc[mt][nt] = mfma16(af, bfr[nt], acc[mt][nt]);
        }
    }
    #pragma unroll
    for (int mt = 0; mt < 4; ++mt)
        #pragma unroll
        for (int nt = 0; nt < 4; ++nt)
            #pragma unroll
            for (int r = 0; r < 4; ++r)
                Hs[nt * 16 + n16][w * 64 + mt * 16 + quad * 4 + r] =
                    (__bf16)fmaxf(acc[mt][nt][r], 0.0f);
    __syncthreads();

    // phase 3: h2 = W2 @ relu(h1)
    #pragma unroll
    for (int mt = 0; mt < 4; ++mt)
        #pragma unroll
        for (int nt = 0; nt < 4; ++nt) acc[mt][nt] = zero4;
    #pragma unroll
    for (int ks = 0; ks < 8; ++ks) {
        bf16x8 bfr[4];
        #pragma unroll
        for (int nt = 0; nt < 4; ++nt)
            bfr[nt] = *(const bf16x8*)&Hs[nt * 16 + n16][ks * 32 + quad * 8];
        #pragma unroll
        for (int mt = 0; mt < 4; ++mt) {
            bf16x8 af = W2v[(w * 64 + mt * 16 + n16) * 32 + ks * 4 + quad];
            #pragma unroll
            for (int nt = 0; nt < 4; ++nt)
                acc[mt][nt] = mfma16(af, bfr[nt], acc[mt][nt]);
        }
    }

    // log-softmax over 256 rows per column
    float lmax[4], lsum[4];
    #pragma unroll
    for (int nt = 0; nt < 4; ++nt) {
        float m = -1e30f;
        #pragma unroll
        for (int mt = 0; mt < 4; ++mt)
            #pragma unroll
            for (int r = 0; r < 4; ++r) m = fmaxf(m, acc[mt][nt][r]);
        m = fmaxf(m, __shfl_xor(m, 16, 64));
        m = fmaxf(m, __shfl_xor(m, 32, 64));
        lmax[nt] = m;
    }
    if (quad == 0) {
        #pragma unroll
        for (int nt = 0; nt < 4; ++nt) redm[w][nt][n16] = lmax[nt];
    }
    __syncthreads();
    #pragma unroll
    for (int nt = 0; nt < 4; ++nt) {
        float m = redm[0][nt][n16];
        m = fmaxf(m, redm[1][nt][n16]);
        m = fmaxf(m, redm[2][nt][n16]);
        m = fmaxf(m, redm[3][nt][n16]);
        lmax[nt] = m;
        float s = 0.0f;
        #pragma unroll
        for (int mt = 0; mt < 4; ++mt)
            #pragma unroll
            for (int r = 0; r < 4; ++r) s += __expf(acc[mt][nt][r] - m);
        s += __shfl_xor(s, 16, 64);
        s += __shfl_xor(s, 32, 64);
        lsum[nt] = s;
    }
    if (quad == 0) {
        #pragma unroll
        for (int nt = 0; nt < 4; ++nt) reds[w][nt][n16] = lsum[nt];
    }
    __syncthreads();
    #pragma unroll
    for (int nt = 0; nt < 4; ++nt) {
        float s = reds[0][nt][n16] + reds[1][nt][n16] + reds[2][nt][n16] + reds[3][nt][n16];
        float lse = lmax[nt] + logf(s);
        int t = t0 + nt * 16 + n16;
        #pragma unroll
        for (int mt = 0; mt < 4; ++mt)
            #pragma unroll
            for (int r = 0; r < 4; ++r) {
                int o = w * 64 + mt * 16 + quad * 4 + r;
                out[((size_t)(b * SKIPN + o)) * T_TOT + t] = acc[mt][nt][r] - lse;
            }
    }
}

extern "C" void kernel_launch(void* const* d_in, const int* in_sizes, int n_in,
                              void* d_out, int out_size, void* d_ws, size_t ws_size,
                              hipStream_t stream) {
    const float* lf       = (const float*)d_in[0];
    const float* gold     = (const float*)d_in[1];
    const float* embed_w  = (const float*)d_in[2];
    const float* embed_b  = (const float*)d_in[3];
    const float* up_w     = (const float*)d_in[4];
    const float* up_b     = (const float*)d_in[5];
    const float* proj_w   = (const float*)d_in[6];
    const float* proj_b   = (const float*)d_in[7];
    const float* dil_w    = (const float*)d_in[8];
    const float* dil_b    = (const float*)d_in[9];
    const float* skip_w   = (const float*)d_in[10];
    const float* skip_b   = (const float*)d_in[11];
    const float* res_w    = (const float*)d_in[12];
    const float* res_b    = (const float*)d_in[13];
    const float* out1_w   = (const float*)d_in[14];
    const float* out2_w   = (const float*)d_in[15];

    __bf16* A1  = (__bf16*)d_ws;          // 24*128*128 = 393216
    __bf16* A3  = A1 + 393216;            // 23*64*64   = 94208
    __bf16* As1 = A3 + 94208;             // 256*1536   = 393216
    __bf16* Ao1 = As1 + 393216;           // 65536
    __bf16* Ao2 = Ao1 + 65536;            // 65536
    __bf16* G   = Ao2 + 65536;            // 24*2*300*4096 = 58982400
    float* sbsum  = (float*)(G + (size_t)NLAYER * NB * NTILE * NT * HD);
    float* y_up   = sbsum + 256;
    float* z      = y_up + NB * LFN * 256;
    float* x_a    = z + NB * 3072 * 256;
    float* x_b    = x_a + NB * HD * T_TOT;

    prep_kernel<<<(24 * 128 * 128 + 255) / 256, 256, 0, stream>>>(
        dil_w, skip_w, skip_b, res_w, out1_w, out2_w, A1, A3, As1, Ao1, Ao2, sbsum);
    up_kernel  <<<(NB * LFN * 256 + 255) / 256, 256, 0, stream>>>(lf, up_w, up_b, y_up);
    proj_kernel<<<(NB * 3072 * 256) / 256,      256, 0, stream>>>(y_up, proj_w, proj_b, z);
    embed_kernel<<<(NB * HD * T_TOT) / 256,     256, 0, stream>>>(gold, embed_w, embed_b, x_a);

    float* xin = x_a;
    float* xout = x_b;
    for (int i = 0; i < NLAYER; ++i) {
        int d = 1 << (i % 6);
        layer_mfma<<<dim3(NTILE, NB), 256, 0, stream>>>(
            xin, xout, z,
            A1 + (size_t)i * 128 * 128, dil_b + i * 128,
            (i < NLAYER - 1) ? A3 + (size_t)i * 64 * 64 : A3,
            (i < NLAYER - 1) ? res_b + i * 64 : res_b,
            G, i, d, (i < NLAYER - 1) ? 1 : 0);
        float* tmp = xin; xin = xout; xout = tmp;
    }

    head_mfma<<<dim3(NTILE, NB), 256, 0, stream>>>(G, As1, sbsum, Ao1, Ao2, (float*)d_out);
}

// Round 5
// 408.322 us; speedup vs baseline: 19.7138x; 1.7971x over previous
//
#include <hip/hip_runtime.h>
#include <math.h>

#define T_TOT 19200
#define HD    64
#define SKIPN 256
#define NLAYER 24
#define LFN   80
#define NB    2
#define NTL   128            // valid t per layer-group block
#define HALO  64             // staged left halo (needs 63)
#define XR    (NTL + HALO)   // 192 staged rows
#define NGT   (T_TOT / NTL)  // 150
#define NOH   64             // t-tile per head block
#define NTH   (T_TOT / NOH)  // 300

typedef float  f32x4  __attribute__((ext_vector_type(4)));
typedef __bf16 bf16x8 __attribute__((ext_vector_type(8)));
typedef __bf16 bf16x4 __attribute__((ext_vector_type(4)));

__device__ __forceinline__ f32x4 mfma16(bf16x8 a, bf16x8 b, f32x4 c) {
    return __builtin_amdgcn_mfma_f32_16x16x32_bf16(a, b, c, 0, 0, 0);
}

// ---------------- prep: convert weights to bf16 in MFMA fragment order ----------------
// Fragment order: [...][mtile][ks][lane(64)][j(8)] so a wave's A-frag load is
// 64 lanes x 16B contiguous. row = mtile*16 + (lane&15), k = ks*32 + (lane>>4)*8 + j.
__global__ __launch_bounds__(256) void prep_kernel(
    const float* __restrict__ dil_w, const float* __restrict__ skip_w,
    const float* __restrict__ skip_b, const float* __restrict__ res_w,
    const float* __restrict__ out1_w, const float* __restrict__ out2_w,
    __bf16* __restrict__ A1f, __bf16* __restrict__ Asf, __bf16* __restrict__ A3f,
    __bf16* __restrict__ Ao1f, __bf16* __restrict__ Ao2f, float* __restrict__ sbsum)
{
    int idx = blockIdx.x * 256 + threadIdx.x;
    if (idx < 24 * 128 * 128) {
        {   // A1f: l(24) mt(8) ks(4) lane j ; k<64 -> tap(t-d), k>=64 -> tap(t)
            int j = idx & 7, lane = (idx >> 3) & 63, ks = (idx >> 9) & 3;
            int mt = (idx >> 11) & 7, l = idx >> 14;
            int row = mt * 16 + (lane & 15);
            int k   = ks * 32 + (lane >> 4) * 8 + j;
            A1f[idx] = (__bf16)dil_w[((l * 128 + row) * 64 + (k & 63)) * 2 + (k >> 6)];
        }
        {   // Asf: l(24) mt(16) ks(2) lane j
            int j = idx & 7, lane = (idx >> 3) & 63, ks = (idx >> 9) & 1;
            int mt = (idx >> 10) & 15, l = idx >> 14;
            int row = mt * 16 + (lane & 15);
            int k   = ks * 32 + (lane >> 4) * 8 + j;
            Asf[idx] = (__bf16)skip_w[(l * 256 + row) * 64 + k];
        }
    }
    if (idx < 23 * 64 * 64) {   // A3f: l(23) mt(4) ks(2) lane j
        int j = idx & 7, lane = (idx >> 3) & 63, ks = (idx >> 9) & 1;
        int mt = (idx >> 10) & 3, l = idx >> 12;
        int row = mt * 16 + (lane & 15);
        int k   = ks * 32 + (lane >> 4) * 8 + j;
        A3f[idx] = (__bf16)res_w[(l * 64 + row) * 64 + k];
    }
    if (idx < 256 * 256) {      // Ao1f/Ao2f: mt(16) ks(8) lane j
        int j = idx & 7, lane = (idx >> 3) & 63, ks = (idx >> 9) & 7;
        int mt = idx >> 12;
        int row = mt * 16 + (lane & 15);
        int k   = ks * 32 + (lane >> 4) * 8 + j;
        Ao1f[idx] = (__bf16)out1_w[row * 256 + k];
        Ao2f[idx] = (__bf16)out2_w[row * 256 + k];
    }
    if (idx < 256) {
        float s = 0.0f;
        #pragma unroll
        for (int l = 0; l < NLAYER; ++l) s += skip_b[l * 256 + idx];
        sbsum[idx] = s;
    }
}

// ---------------- upsample stage 1 ----------------
__global__ __launch_bounds__(256) void up_kernel(
    const float* __restrict__ lf, const float* __restrict__ up_w,
    const float* __restrict__ up_b, float* __restrict__ y_up)
{
    int idx = blockIdx.x * 256 + threadIdx.x;
    if (idx >= NB * LFN * 256) return;
    int t4 = idx & 255;
    int g  = (idx >> 8) % LFN;
    int b  = idx / (LFN * 256);
    int l = t4 >> 2, k = t4 & 3;
    float acc = up_b[g];
    const float* lfp = lf + (b * 64 + l) * LFN;
    #pragma unroll 8
    for (int f = 0; f < LFN; ++f)
        acc += lfp[f] * up_w[(f * LFN + g) * 4 + k];
    y_up[idx] = acc;
}

// ---------------- upsample stage 2 ----------------
__global__ __launch_bounds__(256) void proj_kernel(
    const float* __restrict__ y_up, const float* __restrict__ proj_w,
    const float* __restrict__ proj_b, float* __restrict__ z)
{
    int idx = blockIdx.x * 256 + threadIdx.x;
    if (idx >= NB * 3072 * 256) return;
    int t4 = idx & 255;
    int o  = (idx >> 8) % 3072;
    int b  = idx / (3072 * 256);
    float acc = proj_b[o];
    const float* yp = y_up + b * LFN * 256 + t4;
    const float* wp = proj_w + o * LFN;
    #pragma unroll 8
    for (int g = 0; g < LFN; ++g)
        acc += wp[g] * yp[g * 256];
    z[idx] = acc;
}

// ---------------- 6 fused WaveNet layers (one dilation cycle) ----------------
// grid (NGT, NB), 256 thr. Block stages x for t in [t0-64, t0+128) in LDS and
// runs layers L0..L0+5 locally; halo cols become garbage progressively (2^j-1
// per layer) but stay bounded; only valid cols [t0, t0+128) are emitted.
__global__ __launch_bounds__(256, 2) void layer_group(
    const float* __restrict__ gold, const float* __restrict__ ew,
    const float* __restrict__ eb,
    const __bf16* __restrict__ xg_in, __bf16* __restrict__ xg_out,
    const float* __restrict__ zbuf, const float* __restrict__ dil_b,
    const float* __restrict__ res_b,
    const __bf16* __restrict__ A1f, const __bf16* __restrict__ A3f,
    __bf16* __restrict__ G, int L0, int first, int last)
{
    __shared__ __bf16 xh[XR][72];   // x, row t0-64+r
    __shared__ __bf16 Gs[XR][72];   // gated
    __shared__ float  zs[4][128];   // cond+bias q-window

    const int b    = blockIdx.y;
    const int t0   = blockIdx.x * NTL;
    const int tid  = threadIdx.x;
    const int lane = tid & 63;
    const int w    = tid >> 6;
    const int n16  = lane & 15;
    const int quad = lane >> 4;
    const int q0   = ((t0 - HALO > 0) ? t0 - HALO : 0) / 75;

    bf16x8 z8;
    #pragma unroll
    for (int u = 0; u < 8; ++u) z8[u] = (__bf16)0.0f;

    // ---- stage x tile [t0-64, t0+128) ----
    if (first) {
        for (int idx = tid; idx < XR * 8; idx += 256) {
            int r = idx >> 3, hc = (idx & 7) * 8;
            int t = t0 - HALO + r;
            bf16x8 v = z8;
            if (t >= 0) {
                float gv = gold[b * T_TOT + t];
                #pragma unroll
                for (int u = 0; u < 8; ++u)
                    v[u] = (__bf16)(gv * ew[hc + u] + eb[hc + u]);
            }
            *(bf16x8*)&xh[r][hc] = v;
        }
    } else {
        for (int idx = tid; idx < XR * 8; idx += 256) {
            int r = idx >> 3, hc = (idx & 7) * 8;
            int t = t0 - HALO + r;
            bf16x8 v = (t >= 0)
                ? *(const bf16x8*)&xg_in[((size_t)b * T_TOT + t) * 64 + hc] : z8;
            *(bf16x8*)&xh[r][hc] = v;
        }
    }

    const bf16x8* A1v = (const bf16x8*)A1f;
    const bf16x8* A3v = (const bf16x8*)A3f;
    f32x4 zero4 = {0.0f, 0.0f, 0.0f, 0.0f};

    for (int j = 0; j < 6; ++j) {
        const int l = L0 + j;
        const int d = 1 << j;

        // stage cond+bias (4-q window covers t in [t0-64, t0+128))
        for (int idx = tid; idx < 512; idx += 256) {
            int qq = idx >> 7, o = idx & 127;
            int q = q0 + qq; if (q > 255) q = 255;
            zs[qq][o] = dil_b[l * 128 + o] +
                        zbuf[((size_t)(b * 3072 + l * 128 + o)) * 256 + q];
        }
        // A1 fragments: wave w owns rows [w*16,+16) (tanh) and [64+w*16,+16) (sigm)
        bf16x8 a1a[4], a1b[4];
        #pragma unroll
        for (int ks = 0; ks < 4; ++ks) {
            a1a[ks] = A1v[((l * 8 + w) * 4 + ks) * 64 + lane];
            a1b[ks] = A1v[((l * 8 + 4 + w) * 4 + ks) * 64 + lane];
        }
        __syncthreads();   // A: zs + x staged / prev-layer res done

        // GEMM1 + gate, 12 n-tiles covering all 192 rows
        #pragma unroll
        for (int nt = 0; nt < 12; ++nt) {
            int nn = nt * 16 + n16;
            int rm = (nn >= d) ? nn - d : 0;
            bf16x8 b0 = *(const bf16x8*)&xh[rm][quad * 8];
            bf16x8 b1 = *(const bf16x8*)&xh[rm][32 + quad * 8];
            bf16x8 b2 = *(const bf16x8*)&xh[nn][quad * 8];
            bf16x8 b3 = *(const bf16x8*)&xh[nn][32 + quad * 8];
            f32x4 aa = zero4, ab = zero4;
            aa = mfma16(a1a[0], b0, aa); ab = mfma16(a1b[0], b0, ab);
            aa = mfma16(a1a[1], b1, aa); ab = mfma16(a1b[1], b1, ab);
            aa = mfma16(a1a[2], b2, aa); ab = mfma16(a1b[2], b2, ab);
            aa = mfma16(a1a[3], b3, aa); ab = mfma16(a1b[3], b3, ab);

            int tt = t0 - HALO + nn;
            int qq = ((tt > 0) ? tt : 0) / 75 - q0;
            bf16x4 g4;
            #pragma unroll
            for (int r = 0; r < 4; ++r) {
                int o = w * 16 + quad * 4 + r;
                float ya = aa[r] + zs[qq][o];
                float yb = ab[r] + zs[qq][o + 64];
                float th = 1.0f - 2.0f * __builtin_amdgcn_rcpf(__expf(2.0f * ya) + 1.0f);
                float sg = __builtin_amdgcn_rcpf(1.0f + __expf(-yb));
                g4[r] = (__bf16)(th * sg);
            }
            *(bf16x4*)&Gs[nn][w * 16 + quad * 4] = g4;
        }
        __syncthreads();   // B: Gs complete

        // emit G for valid cols [t0, t0+128)
        __bf16* Gl = G + (((size_t)l * NB + b) * T_TOT + t0) * 64;
        for (int idx = tid; idx < 128 * 8; idx += 256) {
            int rr = idx >> 3, hc = (idx & 7) * 8;
            *(bf16x8*)&Gl[rr * 64 + hc] = *(const bf16x8*)&Gs[HALO + rr][hc];
        }

        // residual: x += res_w @ g + res_b (all rows, in LDS)
        if (l < NLAYER - 1) {
            bf16x8 a3[2];
            #pragma unroll
            for (int ks = 0; ks < 2; ++ks)
                a3[ks] = A3v[((l * 4 + w) * 2 + ks) * 64 + lane];
            int o0 = w * 16 + quad * 4;
            f32x4 rb = *(const f32x4*)&res_b[l * 64 + o0];
            #pragma unroll
            for (int nt = 0; nt < 12; ++nt) {
                int nn = nt * 16 + n16;
                bf16x8 g0 = *(const bf16x8*)&Gs[nn][quad * 8];
                bf16x8 g1 = *(const bf16x8*)&Gs[nn][32 + quad * 8];
                f32x4 ar = zero4;
                ar = mfma16(a3[0], g0, ar);
                ar = mfma16(a3[1], g1, ar);
                bf16x4 xo = *(const bf16x4*)&xh[nn][o0];
                bf16x4 xn;
                #pragma unroll
                for (int r = 0; r < 4; ++r)
                    xn[r] = (__bf16)((float)xo[r] + ar[r] + rb[r]);
                *(bf16x4*)&xh[nn][o0] = xn;
            }
        }
        // next iteration's sync A orders these writes vs next GEMM1 reads
    }

    if (!last) {
        __syncthreads();
        for (int idx = tid; idx < 128 * 8; idx += 256) {
            int rr = idx >> 3, hc = (idx & 7) * 8;
            *(bf16x8*)&xg_out[((size_t)b * T_TOT + t0 + rr) * 64 + hc] =
                *(const bf16x8*)&xh[HALO + rr][hc];
        }
    }
}

// ---------------- fused head: skip (K=1536) + out1 + out2 + log-softmax ----------------
// grid (NTH, NB), 256 thr, 4 blocks/CU. Wave w owns rows [w*64, w*64+64).
__global__ __launch_bounds__(256, 4) void head_mfma(
    const __bf16* __restrict__ G, const __bf16* __restrict__ Asf,
    const float* __restrict__ sbsum, const __bf16* __restrict__ Ao1f,
    const __bf16* __restrict__ Ao2f, float* __restrict__ out)
{
    __shared__ __bf16 Vs[NOH][264];   // B-operand buffer (reused for h1)
    __shared__ float redm[4][4][16];
    __shared__ float reds[4][4][16];

    const int b    = blockIdx.y;
    const int t0   = blockIdx.x * NOH;
    const int tid  = threadIdx.x;
    const int lane = tid & 63;
    const int w    = tid >> 6;
    const int n16  = lane & 15;
    const int quad = lane >> 4;

    f32x4 zero4 = {0.0f, 0.0f, 0.0f, 0.0f};
    f32x4 acc[4][4];
    #pragma unroll
    for (int mt = 0; mt < 4; ++mt)
        #pragma unroll
        for (int nt = 0; nt < 4; ++nt) acc[mt][nt] = zero4;

    const bf16x8* Asv = (const bf16x8*)Asf;

    // phase 1: skip = sum_l skip_w[l] @ g[l]
    for (int l = 0; l < NLAYER; ++l) {
        const __bf16* Gl = G + (((size_t)l * NB + b) * T_TOT + t0) * 64;
        #pragma unroll
        for (int ks = 0; ks < 2; ++ks) {
            bf16x8 bfr[4];
            #pragma unroll
            for (int nt = 0; nt < 4; ++nt)
                bfr[nt] = *(const bf16x8*)&Gl[(nt * 16 + n16) * 64 + ks * 32 + quad * 8];
            #pragma unroll
            for (int mt = 0; mt < 4; ++mt) {
                bf16x8 af = Asv[((l * 16 + w * 4 + mt) * 2 + ks) * 64 + lane];
                #pragma unroll
                for (int nt = 0; nt < 4; ++nt)
                    acc[mt][nt] = mfma16(af, bfr[nt], acc[mt][nt]);
            }
        }
    }
    // epilogue: +bias-sum, relu -> Vs
    {
        int s0 = w * 64 + quad * 4;   // + mt*16
        #pragma unroll
        for (int mt = 0; mt < 4; ++mt) {
            #pragma unroll
            for (int nt = 0; nt < 4; ++nt) {
                bf16x4 v4;
                #pragma unroll
                for (int r = 0; r < 4; ++r)
                    v4[r] = (__bf16)fmaxf(acc[mt][nt][r] + sbsum[s0 + mt * 16 + r], 0.0f);
                *(bf16x4*)&Vs[nt * 16 + n16][s0 + mt * 16] = v4;
            }
        }
    }
    __syncthreads();

    const bf16x8* W1v = (const bf16x8*)Ao1f;
    const bf16x8* W2v = (const bf16x8*)Ao2f;

    // phase 2: h1 = relu(W1 @ v), K=256
    #pragma unroll
    for (int mt = 0; mt < 4; ++mt)
        #pragma unroll
        for (int nt = 0; nt < 4; ++nt) acc[mt][nt] = zero4;
    #pragma unroll
    for (int ks = 0; ks < 8; ++ks) {
        bf16x8 bfr[4];
        #pragma unroll
        for (int nt = 0; nt < 4; ++nt)
            bfr[nt] = *(const bf16x8*)&Vs[nt * 16 + n16][ks * 32 + quad * 8];
        #pragma unroll
        for (int mt = 0; mt < 4; ++mt) {
            bf16x8 af = W1v[((w * 4 + mt) * 8 + ks) * 64 + lane];
            #pragma unroll
            for (int nt = 0; nt < 4; ++nt)
                acc[mt][nt] = mfma16(af, bfr[nt], acc[mt][nt]);
        }
    }
    __syncthreads();   // all Vs reads done; safe to overwrite
    #pragma unroll
    for (int mt = 0; mt < 4; ++mt)
        #pragma unroll
        for (int nt = 0; nt < 4; ++nt) {
            int o0 = w * 64 + mt * 16 + quad * 4;
            bf16x4 v4;
            #pragma unroll
            for (int r = 0; r < 4; ++r)
                v4[r] = (__bf16)fmaxf(acc[mt][nt][r], 0.0f);
            *(bf16x4*)&Vs[nt * 16 + n16][o0] = v4;
        }
    __syncthreads();

    // phase 3: h2 = W2 @ relu(h1)
    #pragma unroll
    for (int mt = 0; mt < 4; ++mt)
        #pragma unroll
        for (int nt = 0; nt < 4; ++nt) acc[mt][nt] = zero4;
    #pragma unroll
    for (int ks = 0; ks < 8; ++ks) {
        bf16x8 bfr[4];
        #pragma unroll
        for (int nt = 0; nt < 4; ++nt)
            bfr[nt] = *(const bf16x8*)&Vs[nt * 16 + n16][ks * 32 + quad * 8];
        #pragma unroll
        for (int mt = 0; mt < 4; ++mt) {
            bf16x8 af = W2v[((w * 4 + mt) * 8 + ks) * 64 + lane];
            #pragma unroll
            for (int nt = 0; nt < 4; ++nt)
                acc[mt][nt] = mfma16(af, bfr[nt], acc[mt][nt]);
        }
    }

    // log-softmax over 256 channels per column
    float lmax[4], lsum[4];
    #pragma unroll
    for (int nt = 0; nt < 4; ++nt) {
        float m = -1e30f;
        #pragma unroll
        for (int mt = 0; mt < 4; ++mt)
            #pragma unroll
            for (int r = 0; r < 4; ++r) m = fmaxf(m, acc[mt][nt][r]);
        m = fmaxf(m, __shfl_xor(m, 16, 64));
        m = fmaxf(m, __shfl_xor(m, 32, 64));
        lmax[nt] = m;
    }
    if (quad == 0) {
        #pragma unroll
        for (int nt = 0; nt < 4; ++nt) redm[w][nt][n16] = lmax[nt];
    }
    __syncthreads();
    #pragma unroll
    for (int nt = 0; nt < 4; ++nt) {
        float m = redm[0][nt][n16];
        m = fmaxf(m, redm[1][nt][n16]);
        m = fmaxf(m, redm[2][nt][n16]);
        m = fmaxf(m, redm[3][nt][n16]);
        lmax[nt] = m;
        float s = 0.0f;
        #pragma unroll
        for (int mt = 0; mt < 4; ++mt)
            #pragma unroll
            for (int r = 0; r < 4; ++r) s += __expf(acc[mt][nt][r] - m);
        s += __shfl_xor(s, 16, 64);
        s += __shfl_xor(s, 32, 64);
        lsum[nt] = s;
    }
    if (quad == 0) {
        #pragma unroll
        for (int nt = 0; nt < 4; ++nt) reds[w][nt][n16] = lsum[nt];
    }
    __syncthreads();
    #pragma unroll
    for (int nt = 0; nt < 4; ++nt) {
        float s = reds[0][nt][n16] + reds[1][nt][n16] +
                  reds[2][nt][n16] + reds[3][nt][n16];
        float lse = lmax[nt] + logf(s);
        int t = t0 + nt * 16 + n16;
        #pragma unroll
        for (int mt = 0; mt < 4; ++mt)
            #pragma unroll
            for (int r = 0; r < 4; ++r) {
                int o = w * 64 + mt * 16 + quad * 4 + r;
                out[((size_t)(b * SKIPN + o)) * T_TOT + t] = acc[mt][nt][r] - lse;
            }
    }
}

extern "C" void kernel_launch(void* const* d_in, const int* in_sizes, int n_in,
                              void* d_out, int out_size, void* d_ws, size_t ws_size,
                              hipStream_t stream) {
    const float* lf       = (const float*)d_in[0];
    const float* gold     = (const float*)d_in[1];
    const float* embed_w  = (const float*)d_in[2];
    const float* embed_b  = (const float*)d_in[3];
    const float* up_w     = (const float*)d_in[4];
    const float* up_b     = (const float*)d_in[5];
    const float* proj_w   = (const float*)d_in[6];
    const float* proj_b   = (const float*)d_in[7];
    const float* dil_w    = (const float*)d_in[8];
    const float* dil_b    = (const float*)d_in[9];
    const float* skip_w   = (const float*)d_in[10];
    const float* skip_b   = (const float*)d_in[11];
    const float* res_w    = (const float*)d_in[12];
    const float* res_b    = (const float*)d_in[13];
    const float* out1_w   = (const float*)d_in[14];
    const float* out2_w   = (const float*)d_in[15];

    __bf16* A1f  = (__bf16*)d_ws;          // 393216
    __bf16* Asf  = A1f + 393216;           // 393216
    __bf16* A3f  = Asf + 393216;           // 94208
    __bf16* Ao1f = A3f + 94208;            // 65536
    __bf16* Ao2f = Ao1f + 65536;           // 65536
    __bf16* G    = Ao2f + 65536;           // 24*2*19200*64 = 58982400
    __bf16* xga  = G + (size_t)NLAYER * NB * T_TOT * HD;   // 2457600
    __bf16* xgb  = xga + (size_t)NB * T_TOT * HD;          // 2457600
    float*  sbsum = (float*)(xgb + (size_t)NB * T_TOT * HD);
    float*  y_up  = sbsum + 256;
    float*  zbuf  = y_up + NB * LFN * 256;                 // 2*3072*256

    prep_kernel<<<(24 * 128 * 128 + 255) / 256, 256, 0, stream>>>(
        dil_w, skip_w, skip_b, res_w, out1_w, out2_w,
        A1f, Asf, A3f, Ao1f, Ao2f, sbsum);
    up_kernel  <<<(NB * LFN * 256 + 255) / 256, 256, 0, stream>>>(lf, up_w, up_b, y_up);
    proj_kernel<<<(NB * 3072 * 256) / 256,      256, 0, stream>>>(y_up, proj_w, proj_b, zbuf);

    const __bf16* xin[4] = { xga, xga, xgb, xga };
    __bf16*       xout[4] = { xga, xgb, xga, xgb };
    for (int g = 0; g < 4; ++g) {
        layer_group<<<dim3(NGT, NB), 256, 0, stream>>>(
            gold, embed_w, embed_b, xin[g], xout[g],
            zbuf, dil_b, res_b, A1f, A3f, G,
            6 * g, (g == 0) ? 1 : 0, (g == 3) ? 1 : 0);
    }

    head_mfma<<<dim3(NTH, NB), 256, 0, stream>>>(G, Asf, sbsum, Ao1f, Ao2f, (float*)d_out);
}

// Round 6
// 382.468 us; speedup vs baseline: 21.0463x; 1.0676x over previous
//
#include <hip/hip_runtime.h>
#include <math.h>

#define T_TOT 19200
#define HD    64
#define SKIPN 256
#define NLAYER 24
#define LFN   80
#define NB    2
#define NTL   128            // valid t per layer-group block
#define HALO  64             // staged left halo (needs 63)
#define XR    (NTL + HALO)   // 192 staged rows
#define NGT   (T_TOT / NTL)  // 150
#define NOH   32             // t-tile per head block
#define NTH   (T_TOT / NOH)  // 600
#define NCH   (T_TOT / 32)   // 600 G chunks per batch

typedef float  f32x4  __attribute__((ext_vector_type(4)));
typedef __bf16 bf16x8 __attribute__((ext_vector_type(8)));
typedef __bf16 bf16x4 __attribute__((ext_vector_type(4)));

__device__ __forceinline__ f32x4 mfma16(bf16x8 a, bf16x8 b, f32x4 c) {
    return __builtin_amdgcn_mfma_f32_16x16x32_bf16(a, b, c, 0, 0, 0);
}

// ---------------- prep: convert weights to bf16 in MFMA fragment order ----------------
// Fragment order: [...][mtile][ks][lane(64)][j(8)]; row = mtile*16 + (lane&15),
// k = ks*32 + (lane>>4)*8 + j.
__global__ __launch_bounds__(256) void prep_kernel(
    const float* __restrict__ dil_w, const float* __restrict__ skip_w,
    const float* __restrict__ skip_b, const float* __restrict__ res_w,
    const float* __restrict__ out1_w, const float* __restrict__ out2_w,
    __bf16* __restrict__ A1f, __bf16* __restrict__ Asf, __bf16* __restrict__ A3f,
    __bf16* __restrict__ Ao1f, __bf16* __restrict__ Ao2f, float* __restrict__ sbsum)
{
    int idx = blockIdx.x * 256 + threadIdx.x;
    if (idx < 24 * 128 * 128) {
        {   // A1f: l(24) mt(8) ks(4) lane j ; k<64 -> tap(t-d), k>=64 -> tap(t)
            int j = idx & 7, lane = (idx >> 3) & 63, ks = (idx >> 9) & 3;
            int mt = (idx >> 11) & 7, l = idx >> 14;
            int row = mt * 16 + (lane & 15);
            int k   = ks * 32 + (lane >> 4) * 8 + j;
            A1f[idx] = (__bf16)dil_w[((l * 128 + row) * 64 + (k & 63)) * 2 + (k >> 6)];
        }
        {   // Asf: l(24) mt(16) ks(2) lane j
            int j = idx & 7, lane = (idx >> 3) & 63, ks = (idx >> 9) & 1;
            int mt = (idx >> 10) & 15, l = idx >> 14;
            int row = mt * 16 + (lane & 15);
            int k   = ks * 32 + (lane >> 4) * 8 + j;
            Asf[idx] = (__bf16)skip_w[(l * 256 + row) * 64 + k];
        }
    }
    if (idx < 23 * 64 * 64) {   // A3f: l(23) mt(4) ks(2) lane j
        int j = idx & 7, lane = (idx >> 3) & 63, ks = (idx >> 9) & 1;
        int mt = (idx >> 10) & 3, l = idx >> 12;
        int row = mt * 16 + (lane & 15);
        int k   = ks * 32 + (lane >> 4) * 8 + j;
        A3f[idx] = (__bf16)res_w[(l * 64 + row) * 64 + k];
    }
    if (idx < 256 * 256) {      // Ao1f/Ao2f: mt(16) ks(8) lane j
        int j = idx & 7, lane = (idx >> 3) & 63, ks = (idx >> 9) & 7;
        int mt = idx >> 12;
        int row = mt * 16 + (lane & 15);
        int k   = ks * 32 + (lane >> 4) * 8 + j;
        Ao1f[idx] = (__bf16)out1_w[row * 256 + k];
        Ao2f[idx] = (__bf16)out2_w[row * 256 + k];
    }
    if (idx < 256) {
        float s = 0.0f;
        #pragma unroll
        for (int l = 0; l < NLAYER; ++l) s += skip_b[l * 256 + idx];
        sbsum[idx] = s;
    }
}

// ---------------- upsample stage 1 ----------------
__global__ __launch_bounds__(256) void up_kernel(
    const float* __restrict__ lf, const float* __restrict__ up_w,
    const float* __restrict__ up_b, float* __restrict__ y_up)
{
    int idx = blockIdx.x * 256 + threadIdx.x;
    if (idx >= NB * LFN * 256) return;
    int t4 = idx & 255;
    int g  = (idx >> 8) % LFN;
    int b  = idx / (LFN * 256);
    int l = t4 >> 2, k = t4 & 3;
    float acc = up_b[g];
    const float* lfp = lf + (b * 64 + l) * LFN;
    #pragma unroll 8
    for (int f = 0; f < LFN; ++f)
        acc += lfp[f] * up_w[(f * LFN + g) * 4 + k];
    y_up[idx] = acc;
}

// ---------------- upsample stage 2 ----------------
__global__ __launch_bounds__(256) void proj_kernel(
    const float* __restrict__ y_up, const float* __restrict__ proj_w,
    const float* __restrict__ proj_b, float* __restrict__ z)
{
    int idx = blockIdx.x * 256 + threadIdx.x;
    if (idx >= NB * 3072 * 256) return;
    int t4 = idx & 255;
    int o  = (idx >> 8) % 3072;
    int b  = idx / (3072 * 256);
    float acc = proj_b[o];
    const float* yp = y_up + b * LFN * 256 + t4;
    const float* wp = proj_w + o * LFN;
    #pragma unroll 8
    for (int g = 0; g < LFN; ++g)
        acc += wp[g] * yp[g * 256];
    z[idx] = acc;
}

// ---------------- 6 fused WaveNet layers (one dilation cycle) ----------------
// grid (NGT, NB), 512 thr (8 waves). Wave w: wm = w&3 owns m-tile wm (rows
// wm*16.. of tanh half AND sigmoid half); wg = w>>2 owns n-tiles [wg*6, wg*6+6).
// Block stages x for t in [t0-64, t0+128); halo cols degrade 2^j-1 per layer.
__global__ __launch_bounds__(512, 4) void layer_group(
    const float* __restrict__ gold, const float* __restrict__ ew,
    const float* __restrict__ eb,
    const __bf16* __restrict__ xg_in, __bf16* __restrict__ xg_out,
    const float* __restrict__ zbuf, const float* __restrict__ dil_b,
    const float* __restrict__ res_b,
    const __bf16* __restrict__ A1f, const __bf16* __restrict__ A3f,
    __bf16* __restrict__ G, int L0, int first, int last)
{
    __shared__ __bf16 xh[XR][72];   // x, row t0-64+r
    __shared__ __bf16 Gs[XR][72];   // gated
    __shared__ float  zs[4][128];   // cond+bias q-window

    const int b    = blockIdx.y;
    const int tb   = blockIdx.x;
    const int t0   = tb * NTL;
    const int tid  = threadIdx.x;
    const int lane = tid & 63;
    const int w    = tid >> 6;       // 0..7
    const int wm   = w & 3;          // m-tile
    const int wg   = w >> 2;         // n-half
    const int n16  = lane & 15;
    const int quad = lane >> 4;
    const int q0   = ((t0 - HALO > 0) ? t0 - HALO : 0) / 75;

    bf16x8 z8;
    #pragma unroll
    for (int u = 0; u < 8; ++u) z8[u] = (__bf16)0.0f;

    // ---- stage x tile [t0-64, t0+128) ----
    if (first) {
        for (int idx = tid; idx < XR * 8; idx += 512) {
            int r = idx >> 3, hc = (idx & 7) * 8;
            int t = t0 - HALO + r;
            bf16x8 v = z8;
            if (t >= 0) {
                float gv = gold[b * T_TOT + t];
                #pragma unroll
                for (int u = 0; u < 8; ++u)
                    v[u] = (__bf16)(gv * ew[hc + u] + eb[hc + u]);
            }
            *(bf16x8*)&xh[r][hc] = v;
        }
    } else {
        for (int idx = tid; idx < XR * 8; idx += 512) {
            int r = idx >> 3, hc = (idx & 7) * 8;
            int t = t0 - HALO + r;
            bf16x8 v = (t >= 0)
                ? *(const bf16x8*)&xg_in[((size_t)b * T_TOT + t) * 64 + hc] : z8;
            *(bf16x8*)&xh[r][hc] = v;
        }
    }

    const bf16x8* A1v = (const bf16x8*)A1f;
    const bf16x8* A3v = (const bf16x8*)A3f;
    f32x4 zero4 = {0.0f, 0.0f, 0.0f, 0.0f};

    for (int j = 0; j < 6; ++j) {
        const int l = L0 + j;
        const int d = 1 << j;

        // stage cond+bias (4-q window covers t in [t0-64, t0+128))
        if (tid < 512) {
            int qq = tid >> 7, o = tid & 127;
            int q = q0 + qq; if (q > 255) q = 255;
            zs[qq][o] = dil_b[l * 128 + o] +
                        zbuf[((size_t)(b * 3072 + l * 128 + o)) * 256 + q];
        }
        // A1 fragments for m-tile wm (tanh rows) and wm+4 (sigmoid rows)
        bf16x8 a1a[4], a1b[4];
        #pragma unroll
        for (int ks = 0; ks < 4; ++ks) {
            a1a[ks] = A1v[((l * 8 + wm) * 4 + ks) * 64 + lane];
            a1b[ks] = A1v[((l * 8 + 4 + wm) * 4 + ks) * 64 + lane];
        }
        __syncthreads();   // A: zs staged + prev-layer res / x staging done

        // GEMM1 + gate over this wave's 6 n-tiles
        #pragma unroll
        for (int nt0 = 0; nt0 < 6; ++nt0) {
            int nt = wg * 6 + nt0;
            int nn = nt * 16 + n16;
            int rm = (nn >= d) ? nn - d : 0;
            bf16x8 b0 = *(const bf16x8*)&xh[rm][quad * 8];
            bf16x8 b1 = *(const bf16x8*)&xh[rm][32 + quad * 8];
            bf16x8 b2 = *(const bf16x8*)&xh[nn][quad * 8];
            bf16x8 b3 = *(const bf16x8*)&xh[nn][32 + quad * 8];
            f32x4 aa = zero4, ab = zero4;
            aa = mfma16(a1a[0], b0, aa); ab = mfma16(a1b[0], b0, ab);
            aa = mfma16(a1a[1], b1, aa); ab = mfma16(a1b[1], b1, ab);
            aa = mfma16(a1a[2], b2, aa); ab = mfma16(a1b[2], b2, ab);
            aa = mfma16(a1a[3], b3, aa); ab = mfma16(a1b[3], b3, ab);

            int tt = t0 - HALO + nn;
            int qq = ((tt > 0) ? tt : 0) / 75 - q0;
            bf16x4 g4;
            #pragma unroll
            for (int r = 0; r < 4; ++r) {
                int o = wm * 16 + quad * 4 + r;
                float ya = aa[r] + zs[qq][o];
                float yb = ab[r] + zs[qq][o + 64];
                float th = 1.0f - 2.0f * __builtin_amdgcn_rcpf(__expf(2.0f * ya) + 1.0f);
                float sg = __builtin_amdgcn_rcpf(1.0f + __expf(-yb));
                g4[r] = (__bf16)(th * sg);
            }
            *(bf16x4*)&Gs[nn][wm * 16 + quad * 4] = g4;
        }
        __syncthreads();   // B: Gs complete

        // emit G for valid cols [t0, t0+128), chunked layout [b][tc][l][t32][h]
        {
            __bf16* Gl = G + (((size_t)(b * NCH + tb * 4)) * NLAYER + l) * 2048;
            for (int idx = tid; idx < 128 * 8; idx += 512) {
                int rr = idx >> 3, hc = (idx & 7) * 8;
                size_t off = (size_t)(rr >> 5) * (NLAYER * 2048) + (rr & 31) * 64 + hc;
                *(bf16x8*)&Gl[off] = *(const bf16x8*)&Gs[HALO + rr][hc];
            }
        }

        // residual: x += res_w @ g + res_b (this wave's n-tiles, in LDS)
        if (l < NLAYER - 1) {
            bf16x8 a3[2];
            #pragma unroll
            for (int ks = 0; ks < 2; ++ks)
                a3[ks] = A3v[((l * 4 + wm) * 2 + ks) * 64 + lane];
            int o0 = wm * 16 + quad * 4;
            f32x4 rb = *(const f32x4*)&res_b[l * 64 + o0];
            #pragma unroll
            for (int nt0 = 0; nt0 < 6; ++nt0) {
                int nn = (wg * 6 + nt0) * 16 + n16;
                bf16x8 g0 = *(const bf16x8*)&Gs[nn][quad * 8];
                bf16x8 g1 = *(const bf16x8*)&Gs[nn][32 + quad * 8];
                f32x4 ar = zero4;
                ar = mfma16(a3[0], g0, ar);
                ar = mfma16(a3[1], g1, ar);
                bf16x4 xo = *(const bf16x4*)&xh[nn][o0];
                bf16x4 xn;
                #pragma unroll
                for (int r = 0; r < 4; ++r)
                    xn[r] = (__bf16)((float)xo[r] + ar[r] + rb[r]);
                *(bf16x4*)&xh[nn][o0] = xn;
            }
        }
        // next iteration's sync A orders these writes vs next GEMM1 reads
    }

    if (!last) {
        __syncthreads();
        for (int idx = tid; idx < 128 * 8; idx += 512) {
            int rr = idx >> 3, hc = (idx & 7) * 8;
            *(bf16x8*)&xg_out[((size_t)b * T_TOT + t0 + rr) * 64 + hc] =
                *(const bf16x8*)&xh[HALO + rr][hc];
        }
    }
}

// ---------------- fused head: skip (K=1536) + out1 + out2 + log-softmax ----------------
// grid (NTH, NB), 256 thr, small LDS -> high blocks/CU. Wave w owns rows [w*64,+64).
__global__ __launch_bounds__(256, 4) void head_mfma(
    const __bf16* __restrict__ G, const __bf16* __restrict__ Asf,
    const float* __restrict__ sbsum, const __bf16* __restrict__ Ao1f,
    const __bf16* __restrict__ Ao2f, float* __restrict__ out)
{
    __shared__ __bf16 Vs[NOH][264];   // B-operand buffer (reused for h1)
    __shared__ float redm[4][2][16];
    __shared__ float reds[4][2][16];

    const int b    = blockIdx.y;
    const int tcb  = blockIdx.x;      // 32-wide t chunk
    const int t0   = tcb * NOH;
    const int tid  = threadIdx.x;
    const int lane = tid & 63;
    const int w    = tid >> 6;
    const int n16  = lane & 15;
    const int quad = lane >> 4;

    f32x4 zero4 = {0.0f, 0.0f, 0.0f, 0.0f};
    f32x4 acc[4][2];
    #pragma unroll
    for (int mt = 0; mt < 4; ++mt)
        #pragma unroll
        for (int nt = 0; nt < 2; ++nt) acc[mt][nt] = zero4;

    const bf16x8* Asv = (const bf16x8*)Asf;
    const __bf16* Gc  = G + ((size_t)(b * NCH + tcb)) * (NLAYER * 2048);

    // phase 1: skip = sum_l skip_w[l] @ g[l]  (contiguous 96KB G stream)
    for (int l = 0; l < NLAYER; ++l) {
        const __bf16* Gl = Gc + l * 2048;
        #pragma unroll
        for (int ks = 0; ks < 2; ++ks) {
            bf16x8 bfr[2];
            #pragma unroll
            for (int nt = 0; nt < 2; ++nt)
                bfr[nt] = *(const bf16x8*)&Gl[(nt * 16 + n16) * 64 + ks * 32 + quad * 8];
            #pragma unroll
            for (int mt = 0; mt < 4; ++mt) {
                bf16x8 af = Asv[((l * 16 + w * 4 + mt) * 2 + ks) * 64 + lane];
                #pragma unroll
                for (int nt = 0; nt < 2; ++nt)
                    acc[mt][nt] = mfma16(af, bfr[nt], acc[mt][nt]);
            }
        }
    }
    // epilogue: +bias-sum, relu -> Vs
    {
        int s0 = w * 64 + quad * 4;
        #pragma unroll
        for (int mt = 0; mt < 4; ++mt)
            #pragma unroll
            for (int nt = 0; nt < 2; ++nt) {
                bf16x4 v4;
                #pragma unroll
                for (int r = 0; r < 4; ++r)
                    v4[r] = (__bf16)fmaxf(acc[mt][nt][r] + sbsum[s0 + mt * 16 + r], 0.0f);
                *(bf16x4*)&Vs[nt * 16 + n16][s0 + mt * 16] = v4;
            }
    }
    __syncthreads();

    const bf16x8* W1v = (const bf16x8*)Ao1f;
    const bf16x8* W2v = (const bf16x8*)Ao2f;

    // phase 2: h1 = relu(W1 @ v), K=256
    #pragma unroll
    for (int mt = 0; mt < 4; ++mt)
        #pragma unroll
        for (int nt = 0; nt < 2; ++nt) acc[mt][nt] = zero4;
    #pragma unroll
    for (int ks = 0; ks < 8; ++ks) {
        bf16x8 bfr[2];
        #pragma unroll
        for (int nt = 0; nt < 2; ++nt)
            bfr[nt] = *(const bf16x8*)&Vs[nt * 16 + n16][ks * 32 + quad * 8];
        #pragma unroll
        for (int mt = 0; mt < 4; ++mt) {
            bf16x8 af = W1v[((w * 4 + mt) * 8 + ks) * 64 + lane];
            #pragma unroll
            for (int nt = 0; nt < 2; ++nt)
                acc[mt][nt] = mfma16(af, bfr[nt], acc[mt][nt]);
        }
    }
    __syncthreads();   // all Vs reads done; safe to overwrite
    #pragma unroll
    for (int mt = 0; mt < 4; ++mt)
        #pragma unroll
        for (int nt = 0; nt < 2; ++nt) {
            int o0 = w * 64 + mt * 16 + quad * 4;
            bf16x4 v4;
            #pragma unroll
            for (int r = 0; r < 4; ++r)
                v4[r] = (__bf16)fmaxf(acc[mt][nt][r], 0.0f);
            *(bf16x4*)&Vs[nt * 16 + n16][o0] = v4;
        }
    __syncthreads();

    // phase 3: h2 = W2 @ relu(h1)
    #pragma unroll
    for (int mt = 0; mt < 4; ++mt)
        #pragma unroll
        for (int nt = 0; nt < 2; ++nt) acc[mt][nt] = zero4;
    #pragma unroll
    for (int ks = 0; ks < 8; ++ks) {
        bf16x8 bfr[2];
        #pragma unroll
        for (int nt = 0; nt < 2; ++nt)
            bfr[nt] = *(const bf16x8*)&Vs[nt * 16 + n16][ks * 32 + quad * 8];
        #pragma unroll
        for (int mt = 0; mt < 4; ++mt) {
            bf16x8 af = W2v[((w * 4 + mt) * 8 + ks) * 64 + lane];
            #pragma unroll
            for (int nt = 0; nt < 2; ++nt)
                acc[mt][nt] = mfma16(af, bfr[nt], acc[mt][nt]);
        }
    }

    // log-softmax over 256 channels per column
    float lmax[2], lsum[2];
    #pragma unroll
    for (int nt = 0; nt < 2; ++nt) {
        float m = -1e30f;
        #pragma unroll
        for (int mt = 0; mt < 4; ++mt)
            #pragma unroll
            for (int r = 0; r < 4; ++r) m = fmaxf(m, acc[mt][nt][r]);
        m = fmaxf(m, __shfl_xor(m, 16, 64));
        m = fmaxf(m, __shfl_xor(m, 32, 64));
        lmax[nt] = m;
    }
    if (quad == 0) {
        #pragma unroll
        for (int nt = 0; nt < 2; ++nt) redm[w][nt][n16] = lmax[nt];
    }
    __syncthreads();
    #pragma unroll
    for (int nt = 0; nt < 2; ++nt) {
        float m = redm[0][nt][n16];
        m = fmaxf(m, redm[1][nt][n16]);
        m = fmaxf(m, redm[2][nt][n16]);
        m = fmaxf(m, redm[3][nt][n16]);
        lmax[nt] = m;
        float s = 0.0f;
        #pragma unroll
        for (int mt = 0; mt < 4; ++mt)
            #pragma unroll
            for (int r = 0; r < 4; ++r) s += __expf(acc[mt][nt][r] - m);
        s += __shfl_xor(s, 16, 64);
        s += __shfl_xor(s, 32, 64);
        lsum[nt] = s;
    }
    if (quad == 0) {
        #pragma unroll
        for (int nt = 0; nt < 2; ++nt) reds[w][nt][n16] = lsum[nt];
    }
    __syncthreads();
    #pragma unroll
    for (int nt = 0; nt < 2; ++nt) {
        float s = reds[0][nt][n16] + reds[1][nt][n16] +
                  reds[2][nt][n16] + reds[3][nt][n16];
        float lse = lmax[nt] + logf(s);
        int t = t0 + nt * 16 + n16;
        #pragma unroll
        for (int mt = 0; mt < 4; ++mt)
            #pragma unroll
            for (int r = 0; r < 4; ++r) {
                int o = w * 64 + mt * 16 + quad * 4 + r;
                out[((size_t)(b * SKIPN + o)) * T_TOT + t] = acc[mt][nt][r] - lse;
            }
    }
}

extern "C" void kernel_launch(void* const* d_in, const int* in_sizes, int n_in,
                              void* d_out, int out_size, void* d_ws, size_t ws_size,
                              hipStream_t stream) {
    const float* lf       = (const float*)d_in[0];
    const float* gold     = (const float*)d_in[1];
    const float* embed_w  = (const float*)d_in[2];
    const float* embed_b  = (const float*)d_in[3];
    const float* up_w     = (const float*)d_in[4];
    const float* up_b     = (const float*)d_in[5];
    const float* proj_w   = (const float*)d_in[6];
    const float* proj_b   = (const float*)d_in[7];
    const float* dil_w    = (const float*)d_in[8];
    const float* dil_b    = (const float*)d_in[9];
    const float* skip_w   = (const float*)d_in[10];
    const float* skip_b   = (const float*)d_in[11];
    const float* res_w    = (const float*)d_in[12];
    const float* res_b    = (const float*)d_in[13];
    const float* out1_w   = (const float*)d_in[14];
    const float* out2_w   = (const float*)d_in[15];

    __bf16* A1f  = (__bf16*)d_ws;          // 393216
    __bf16* Asf  = A1f + 393216;           // 393216
    __bf16* A3f  = Asf + 393216;           // 94208
    __bf16* Ao1f = A3f + 94208;            // 65536
    __bf16* Ao2f = Ao1f + 65536;           // 65536
    __bf16* G    = Ao2f + 65536;           // 2*600*24*2048 = 58982400
    __bf16* xga  = G + (size_t)NB * NCH * NLAYER * 2048;   // 2457600
    __bf16* xgb  = xga + (size_t)NB * T_TOT * HD;          // 2457600
    float*  sbsum = (float*)(xgb + (size_t)NB * T_TOT * HD);
    float*  y_up  = sbsum + 256;
    float*  zbuf  = y_up + NB * LFN * 256;                 // 2*3072*256

    prep_kernel<<<(24 * 128 * 128 + 255) / 256, 256, 0, stream>>>(
        dil_w, skip_w, skip_b, res_w, out1_w, out2_w,
        A1f, Asf, A3f, Ao1f, Ao2f, sbsum);
    up_kernel  <<<(NB * LFN * 256 + 255) / 256, 256, 0, stream>>>(lf, up_w, up_b, y_up);
    proj_kernel<<<(NB * 3072 * 256) / 256,      256, 0, stream>>>(y_up, proj_w, proj_b, zbuf);

    const __bf16* xin[4] = { xga, xga, xgb, xga };
    __bf16*       xout[4] = { xga, xgb, xga, xgb };
    for (int g = 0; g < 4; ++g) {
        layer_group<<<dim3(NGT, NB), 512, 0, stream>>>(
            gold, embed_w, embed_b, xin[g], xout[g],
            zbuf, dil_b, res_b, A1f, A3f, G,
            6 * g, (g == 0) ? 1 : 0, (g == 3) ? 1 : 0);
    }

    head_mfma<<<dim3(NTH, NB), 256, 0, stream>>>(G, Asf, sbsum, Ao1f, Ao2f, (float*)d_out);
}